// Round 1
// baseline (676.886 us; speedup 1.0000x reference)
//
#include <hip/hip_runtime.h>
#include <hip/hip_bf16.h>
#include <stdint.h>

#define TB    64     // batches per block
#define NTHR  128    // threads per block (2 waves)
#define S     5
#define F     12
#define E     32
#define NH    2
#define DH    16
#define OUTD  64
#define SF    60     // S*F
#define SE    160    // S*E

__device__ __forceinline__ uint16_t f2bf(float f) {
  union { float f; uint32_t u; } c; c.f = f;
  uint32_t u = c.u + 0x7fffu + ((c.u >> 16) & 1u);
  return (uint16_t)(u >> 16);
}
__device__ __forceinline__ uint32_t pack2(float lo, float hi) {
  return ((uint32_t)f2bf(lo)) | (((uint32_t)f2bf(hi)) << 16);
}
__device__ __forceinline__ void unpack2(uint32_t w, float& lo, float& hi) {
  union { uint32_t u; float f; } a, b;
  a.u = w << 16; b.u = w & 0xffff0000u;
  lo = a.f; hi = b.f;
}

__global__ __launch_bounds__(NTHR, 2) void fused_exec_encoder(
    const float* __restrict__ x,
    const float* __restrict__ W1,  const float* __restrict__ b1,
    const float* __restrict__ g1,  const float* __restrict__ be1,
    const float* __restrict__ Wqkv,const float* __restrict__ bqkv,
    const float* __restrict__ Wo,  const float* __restrict__ bo,
    const float* __restrict__ g2,  const float* __restrict__ be2,
    const float* __restrict__ W3,  const float* __restrict__ b3,
    const float* __restrict__ g3,  const float* __restrict__ be3,
    float* __restrict__ out)
{
  // h_buf: packed bf16 pairs, layout [pair (s*16+e2)][batch b] -> 80*64 u32 = 20 KB
  __shared__ uint32_t h_buf[(SE/2) * TB];
  __shared__ __align__(16) unsigned char region2[20480]; // o_buf / x_stage / out_tile+scratch
  uint32_t* o_buf     = (uint32_t*)region2;              // 80*64 u32
  float*    x_stage   = (float*)region2;                 // 64*61 floats = 15616 B
  float*    out_tile  = (float*)region2;                 // 64*65 floats = 16640 B
  float*    ln_scratch= (float*)(region2 + 16640);       // 2*64*2 floats = 1024 B

  const int tid = threadIdx.x;
  const int b0  = blockIdx.x * TB;

  // ---------- stage x: coalesced float4 global -> LDS (pad 61 for bank spread)
  {
    const float4* xg = (const float4*)(x + (size_t)b0 * SF);
    for (int i = tid; i < TB * (SF / 4); i += NTHR) {
      float4 v = xg[i];
      int b = i / (SF / 4);
      int j = (i - b * (SF / 4)) * 4;
      float* dst = &x_stage[b * 61 + j];
      dst[0] = v.x; dst[1] = v.y; dst[2] = v.z; dst[3] = v.w;
    }
  }
  __syncthreads();

  // ---------- P1: slot_encoder  (task = (b,s) row)
  for (int r = tid; r < TB * S; r += NTHR) {
    int b = r & (TB - 1);
    int s = __builtin_amdgcn_readfirstlane(r >> 6);
    const float* xr = &x_stage[b * 61 + s * F];
    float xv[F];
#pragma unroll
    for (int f = 0; f < F; ++f) xv[f] = xr[f];
    float t[E];
#pragma unroll
    for (int e = 0; e < E; ++e) {
      float a = b1[e];
#pragma unroll
      for (int f = 0; f < F; ++f) a += xv[f] * W1[e * F + f];
      t[e] = a;
    }
    float mean = 0.f;
#pragma unroll
    for (int e = 0; e < E; ++e) mean += t[e];
    mean *= (1.f / E);
    float var = 0.f;
#pragma unroll
    for (int e = 0; e < E; ++e) { float d = t[e] - mean; var += d * d; }
    var *= (1.f / E);
    float inv = rsqrtf(var + 1e-5f);
#pragma unroll
    for (int e2 = 0; e2 < E / 2; ++e2) {
      float lo = fmaxf((t[2*e2]   - mean) * inv * g1[2*e2]   + be1[2*e2],   0.f);
      float hi = fmaxf((t[2*e2+1] - mean) * inv * g1[2*e2+1] + be1[2*e2+1], 0.f);
      h_buf[(s * (E/2) + e2) * TB + b] = pack2(lo, hi);
    }
  }
  __syncthreads();

  // ---------- P2: MHA (task = (b, head) per thread)
  {
    const int b  = tid & (TB - 1);
    const int hh = __builtin_amdgcn_readfirstlane(tid >> 6);
    float hrow[E];

    // pass K: k[s2][d]
    float kk[S][DH];
#pragma unroll
    for (int s2 = 0; s2 < S; ++s2) {
#pragma unroll
      for (int e2 = 0; e2 < E / 2; ++e2)
        unpack2(h_buf[(s2 * (E/2) + e2) * TB + b], hrow[2*e2], hrow[2*e2+1]);
#pragma unroll
      for (int d = 0; d < DH; ++d) {
        int j = E + hh * DH + d;
        float a = bqkv[j];
#pragma unroll
        for (int e = 0; e < E; ++e) a += hrow[e] * Wqkv[j * E + e];
        kk[s2][d] = a;
      }
    }

    // scores: q computed on the fly
    float sc[S][S];
#pragma unroll
    for (int s1 = 0; s1 < S; ++s1) {
#pragma unroll
      for (int e2 = 0; e2 < E / 2; ++e2)
        unpack2(h_buf[(s1 * (E/2) + e2) * TB + b], hrow[2*e2], hrow[2*e2+1]);
#pragma unroll
      for (int s2 = 0; s2 < S; ++s2) sc[s1][s2] = 0.f;
#pragma unroll
      for (int d = 0; d < DH; ++d) {
        int j = hh * DH + d;
        float q = bqkv[j];
#pragma unroll
        for (int e = 0; e < E; ++e) q += hrow[e] * Wqkv[j * E + e];
#pragma unroll
        for (int s2 = 0; s2 < S; ++s2) sc[s1][s2] += q * kk[s2][d];
      }
    }
    // softmax (scale 1/sqrt(16)=0.25)
#pragma unroll
    for (int s1 = 0; s1 < S; ++s1) {
      float m = -1e30f;
#pragma unroll
      for (int s2 = 0; s2 < S; ++s2) { sc[s1][s2] *= 0.25f; m = fmaxf(m, sc[s1][s2]); }
      float ssum = 0.f;
#pragma unroll
      for (int s2 = 0; s2 < S; ++s2) { float ex = __expf(sc[s1][s2] - m); sc[s1][s2] = ex; ssum += ex; }
      float rs = 1.f / ssum;
#pragma unroll
      for (int s2 = 0; s2 < S; ++s2) sc[s1][s2] *= rs;
    }

    // pass V + PV
    float oacc[S][DH];
#pragma unroll
    for (int s1 = 0; s1 < S; ++s1)
#pragma unroll
      for (int d = 0; d < DH; ++d) oacc[s1][d] = 0.f;
#pragma unroll
    for (int s2 = 0; s2 < S; ++s2) {
#pragma unroll
      for (int e2 = 0; e2 < E / 2; ++e2)
        unpack2(h_buf[(s2 * (E/2) + e2) * TB + b], hrow[2*e2], hrow[2*e2+1]);
#pragma unroll
      for (int d = 0; d < DH; ++d) {
        int j = 2 * E + hh * DH + d;
        float v = bqkv[j];
#pragma unroll
        for (int e = 0; e < E; ++e) v += hrow[e] * Wqkv[j * E + e];
#pragma unroll
        for (int s1 = 0; s1 < S; ++s1) oacc[s1][d] += sc[s1][s2] * v;
      }
    }
    // write o (this head's 16 cols = 8 packed pairs per row)
#pragma unroll
    for (int s1 = 0; s1 < S; ++s1)
#pragma unroll
      for (int dp = 0; dp < DH / 2; ++dp)
        o_buf[(s1 * (E/2) + hh * (DH/2) + dp) * TB + b] = pack2(oacc[s1][2*dp], oacc[s1][2*dp+1]);
  }
  __syncthreads();

  // ---------- P3: out_proj + residual + LN2  (task = (b,s))
  for (int r = tid; r < TB * S; r += NTHR) {
    int b = r & (TB - 1);
    int s = __builtin_amdgcn_readfirstlane(r >> 6);
    float orow[E];
#pragma unroll
    for (int e2 = 0; e2 < E / 2; ++e2)
      unpack2(o_buf[(s * (E/2) + e2) * TB + b], orow[2*e2], orow[2*e2+1]);
    float t[E];
#pragma unroll
    for (int e2 = 0; e2 < E / 2; ++e2) {
      float hlo, hhi;
      unpack2(h_buf[(s * (E/2) + e2) * TB + b], hlo, hhi);
      t[2*e2] = hlo; t[2*e2+1] = hhi;
    }
#pragma unroll
    for (int eo = 0; eo < E; ++eo) {
      float a = bo[eo];
#pragma unroll
      for (int k = 0; k < E; ++k) a += orow[k] * Wo[eo * E + k];
      t[eo] += a;
    }
    float mean = 0.f;
#pragma unroll
    for (int e = 0; e < E; ++e) mean += t[e];
    mean *= (1.f / E);
    float var = 0.f;
#pragma unroll
    for (int e = 0; e < E; ++e) { float d = t[e] - mean; var += d * d; }
    var *= (1.f / E);
    float inv = rsqrtf(var + 1e-5f);
#pragma unroll
    for (int e2 = 0; e2 < E / 2; ++e2) {
      float lo = (t[2*e2]   - mean) * inv * g2[2*e2]   + be2[2*e2];
      float hi = (t[2*e2+1] - mean) * inv * g2[2*e2+1] + be2[2*e2+1];
      h_buf[(s * (E/2) + e2) * TB + b] = pack2(lo, hi); // overwrite with h2
    }
  }
  __syncthreads();

  // ---------- P4: output_proj + LN3  (task = (b, half of 64 outputs))
  {
    const int b    = tid & (TB - 1);
    const int half = __builtin_amdgcn_readfirstlane(tid >> 6);
    float acc[32];
#pragma unroll
    for (int o = 0; o < 32; ++o) acc[o] = b3[half * 32 + o];
    for (int c = 0; c < S; ++c) {          // 5 chunks of 32 over K=160
      float h2[E];
#pragma unroll
      for (int e2 = 0; e2 < E / 2; ++e2)
        unpack2(h_buf[(c * (E/2) + e2) * TB + b], h2[2*e2], h2[2*e2+1]);
#pragma unroll
      for (int o = 0; o < 32; ++o) {
        const float* wr = &W3[(half * 32 + o) * SE + c * E];
#pragma unroll
        for (int e = 0; e < E; ++e) acc[o] += h2[e] * wr[e];
      }
    }
    float ps = 0.f, pq = 0.f;
#pragma unroll
    for (int o = 0; o < 32; ++o) { ps += acc[o]; pq += acc[o] * acc[o]; }
    ln_scratch[(half * TB + b) * 2 + 0] = ps;
    ln_scratch[(half * TB + b) * 2 + 1] = pq;
    __syncthreads();
    float s0 = ln_scratch[(0 * TB + b) * 2 + 0] + ln_scratch[(1 * TB + b) * 2 + 0];
    float q0 = ln_scratch[(0 * TB + b) * 2 + 1] + ln_scratch[(1 * TB + b) * 2 + 1];
    float mean = s0 * (1.f / OUTD);
    float var  = q0 * (1.f / OUTD) - mean * mean;
    float inv  = rsqrtf(var + 1e-5f);
#pragma unroll
    for (int o = 0; o < 32; ++o) {
      int oo = half * 32 + o;
      out_tile[b * 65 + oo] = (acc[o] - mean) * inv * g3[oo] + be3[oo];
    }
  }
  __syncthreads();

  // ---------- coalesced float4 write of the block's (64 x 64) output tile
  {
    float4* og = (float4*)(out + (size_t)b0 * OUTD);
    for (int i = tid; i < TB * OUTD / 4; i += NTHR) {
      int gi = i * 4;
      int b  = gi >> 6;
      int o  = gi & 63;
      float4 v;
      v.x = out_tile[b * 65 + o + 0];
      v.y = out_tile[b * 65 + o + 1];
      v.z = out_tile[b * 65 + o + 2];
      v.w = out_tile[b * 65 + o + 3];
      og[i] = v;
    }
  }
}

extern "C" void kernel_launch(void* const* d_in, const int* in_sizes, int n_in,
                              void* d_out, int out_size, void* d_ws, size_t ws_size,
                              hipStream_t stream) {
  const float* x    = (const float*)d_in[0];
  const float* W1   = (const float*)d_in[1];
  const float* b1   = (const float*)d_in[2];
  const float* g1   = (const float*)d_in[3];
  const float* be1  = (const float*)d_in[4];
  const float* Wqkv = (const float*)d_in[5];
  const float* bqkv = (const float*)d_in[6];
  const float* Wo   = (const float*)d_in[7];
  const float* bo   = (const float*)d_in[8];
  const float* g2   = (const float*)d_in[9];
  const float* be2  = (const float*)d_in[10];
  const float* W3   = (const float*)d_in[11];
  const float* b3   = (const float*)d_in[12];
  const float* g3   = (const float*)d_in[13];
  const float* be3  = (const float*)d_in[14];
  float* out = (float*)d_out;

  const int nbatch  = in_sizes[0] / SF;   // 262144
  const int nblocks = nbatch / TB;        // 4096

  fused_exec_encoder<<<dim3(nblocks), dim3(NTHR), 0, stream>>>(
      x, W1, b1, g1, be1, Wqkv, bqkv, Wo, bo, g2, be2, W3, b3, g3, be3, out);
}

// Round 3
// 141.696 us; speedup vs baseline: 4.7770x; 4.7770x over previous
//
#include <hip/hip_runtime.h>
#include <stdint.h>

#define S    5
#define F    12
#define E    32
#define OUTD 64
#define SF   60
#define TB   32      // batches per block (16 per wave)
#define NTHR 128     // 2 waves, fully independent

// d_ws layout (u32 offsets)
#define WS_W1DUP 0      // [32 rows][16 u32]  slots0-11=W1hi, 12-23=W1hi(dup), 24-31=0
#define WS_W1LO  512    // [32][16]           slots0-11=W1lo, rest 0
#define WS_WQH   1024   // [96][16]
#define WS_WQL   2560   // [96][16]
#define WS_WOH   4096   // [32][16]
#define WS_WOL   4608   // [32][16]
#define WS_W3H   5120   // [64][80]
#define WS_W3L   10240  // [64][80]
#define WS_TOTAL 15360

typedef __attribute__((ext_vector_type(8))) short bf16x8;
typedef __attribute__((ext_vector_type(4))) float f32x4;

union FragU { bf16x8 v; uint32_t u[4]; uint4 q; };

__device__ __forceinline__ uint16_t f2bf(float f) {
  union { float f; uint32_t u; } c; c.f = f;
  uint32_t u = c.u + 0x7fffu + ((c.u >> 16) & 1u);
  return (uint16_t)(u >> 16);
}
__device__ __forceinline__ float bf2f(uint16_t h) {
  union { uint32_t u; float f; } c; c.u = ((uint32_t)h) << 16; return c.f;
}
__device__ __forceinline__ uint32_t pack2(float lo, float hi) {
  return ((uint32_t)f2bf(lo)) | (((uint32_t)f2bf(hi)) << 16);
}
__device__ __forceinline__ void up2(uint32_t w, float& lo, float& hi) {
  union { uint32_t u; float f; } a, b;
  a.u = w << 16; b.u = w & 0xffff0000u;
  lo = a.f; hi = b.f;
}

// ---------------- prep: pack hi/lo bf16 weight planes into d_ws ----------------
__global__ void prep_weights(const float* __restrict__ W1, const float* __restrict__ Wqkv,
                             const float* __restrict__ Wo, const float* __restrict__ W3,
                             uint32_t* __restrict__ ws) {
  int i = blockIdx.x * blockDim.x + threadIdx.x;
  if (i >= WS_TOTAL) return;
  const float* W; int ldk, K, r, j; bool lo, dup = false;
  if (i < 1024)      { W = W1;   ldk = 12;  K = 12;  int t = i;        lo = t >= 512;  t &= 511;  r = t >> 4; j = t & 15; dup = !lo; }
  else if (i < 4096) { W = Wqkv; ldk = 32;  K = 32;  int t = i - 1024; lo = t >= 1536; t %= 1536; r = t >> 4; j = t & 15; }
  else if (i < 5120) { W = Wo;   ldk = 32;  K = 32;  int t = i - 4096; lo = t >= 512;  t &= 511;  r = t >> 4; j = t & 15; }
  else               { W = W3;   ldk = 160; K = 160; int t = i - 5120; lo = t >= 5120; t %= 5120; r = t / 80; j = t % 80; }
  float v2[2];
#pragma unroll
  for (int c = 0; c < 2; ++c) {
    int k = 2 * j + c;
    int m = (k < K) ? k : ((dup && k < 2 * K) ? k - K : -1);
    float w = 0.f;
    if (m >= 0) {
      w = W[r * ldk + m];
      if (lo) w = w - bf2f(f2bf(w));
    }
    v2[c] = w;
  }
  ws[i] = pack2(v2[0], v2[1]);
}

__global__ __launch_bounds__(NTHR, 2) void fused_exec_encoder(
    const float* __restrict__ x,
    const float* __restrict__ b1,
    const float* __restrict__ g1,   const float* __restrict__ be1,
    const float* __restrict__ bqkv,
    const float* __restrict__ bo,
    const float* __restrict__ g2,   const float* __restrict__ be2,
    const float* __restrict__ b3,
    const float* __restrict__ g3,   const float* __restrict__ be3,
    const uint32_t* __restrict__ ws,
    float* __restrict__ out)
{
  // h:  [160 rows][16 u32]  (32 bf16/row, 4x16B chunks, chunk ^ (row&3) swizzle) = 10240 B
  // qkv:[160 rows][48 u32]  (96 bf16/row, 12x16B chunks, same swizzle)           = 30720 B
  __shared__ __align__(16) uint32_t h_lds[160 * 16];
  __shared__ __align__(16) uint32_t qkv_lds[160 * 48];

  const int tid  = threadIdx.x;
  const int lane = tid & 63;
  const int wv   = tid >> 6;          // wave id: owns batches [wv*16, wv*16+16)
  const int li   = lane & 15;         // token/col index within tile
  const int g    = lane >> 4;         // k-group / output-feature group
  const int rowW = wv * 80;           // wave's local token-row base
  const long long b0 = (long long)blockIdx.x * TB;

  // ================= P1: slot_encoder (Linear 12->32 + LN + ReLU) =================
  {
    FragU wdup[2], wlo[2];
#pragma unroll
    for (int t = 0; t < 2; ++t) {
      wdup[t].q = *(const uint4*)&ws[WS_W1DUP + (t * 16 + li) * 16 + g * 4];
      wlo[t].q  = *(const uint4*)&ws[WS_W1LO  + (t * 16 + li) * 16 + g * 4];
    }
    f32x4 binit[2]; float g1v[2][4], e1v[2][4];
#pragma unroll
    for (int t = 0; t < 2; ++t)
#pragma unroll
      for (int r = 0; r < 4; ++r) {
        int n = t * 16 + g * 4 + r;
        binit[t][r] = b1[n]; g1v[t][r] = g1[n]; e1v[t][r] = be1[n];
      }

#pragma unroll
    for (int mt = 0; mt < 5; ++mt) {
      int tokL = rowW + mt * 16 + li;
      int tokG = (int)(b0 * S) + tokL;
      int bat = tokG / 5, s = tokG - bat * 5;
      const float* xp = x + (size_t)bat * SF + s * F;
      FragU xb;
      xb.u[0] = xb.u[1] = xb.u[2] = xb.u[3] = 0u;
      if (g < 3) {
        float4 x0 = *(const float4*)(xp);
        float4 x1 = *(const float4*)(xp + 4);
        float4 x2 = *(const float4*)(xp + 8);
        float xv[12] = {x0.x, x0.y, x0.z, x0.w, x1.x, x1.y, x1.z, x1.w, x2.x, x2.y, x2.z, x2.w};
        float xr[12];
#pragma unroll
        for (int f = 0; f < 12; ++f) xr[f] = xv[f] - bf2f(f2bf(xv[f]));
        if (g == 0) {
          xb.u[0] = pack2(xv[0], xv[1]); xb.u[1] = pack2(xv[2], xv[3]);
          xb.u[2] = pack2(xv[4], xv[5]); xb.u[3] = pack2(xv[6], xv[7]);
        } else if (g == 1) {
          xb.u[0] = pack2(xv[8], xv[9]); xb.u[1] = pack2(xv[10], xv[11]);
          xb.u[2] = pack2(xr[0], xr[1]); xb.u[3] = pack2(xr[2], xr[3]);
        } else {
          xb.u[0] = pack2(xr[4], xr[5]); xb.u[1] = pack2(xr[6], xr[7]);
          xb.u[2] = pack2(xr[8], xr[9]); xb.u[3] = pack2(xr[10], xr[11]);
        }
      }
      f32x4 a0 = __builtin_amdgcn_mfma_f32_16x16x32_bf16(wdup[0].v, xb.v, binit[0], 0, 0, 0);
      a0       = __builtin_amdgcn_mfma_f32_16x16x32_bf16(wlo[0].v,  xb.v, a0,       0, 0, 0);
      f32x4 a1 = __builtin_amdgcn_mfma_f32_16x16x32_bf16(wdup[1].v, xb.v, binit[1], 0, 0, 0);
      a1       = __builtin_amdgcn_mfma_f32_16x16x32_bf16(wlo[1].v,  xb.v, a1,       0, 0, 0);
      float vv[8];
#pragma unroll
      for (int r = 0; r < 4; ++r) { vv[r] = a0[r]; vv[4 + r] = a1[r]; }
      float sm = 0.f, sq = 0.f;
#pragma unroll
      for (int i = 0; i < 8; ++i) { sm += vv[i]; sq = fmaf(vv[i], vv[i], sq); }
      sm += __shfl_xor(sm, 16); sm += __shfl_xor(sm, 32);
      sq += __shfl_xor(sq, 16); sq += __shfl_xor(sq, 32);
      float mean = sm * (1.f / 32.f);
      float inv  = rsqrtf(sq * (1.f / 32.f) - mean * mean + 1e-5f);
#pragma unroll
      for (int t = 0; t < 2; ++t) {
        float u0 = fmaxf((vv[t*4+0] - mean) * inv * g1v[t][0] + e1v[t][0], 0.f);
        float u1 = fmaxf((vv[t*4+1] - mean) * inv * g1v[t][1] + e1v[t][1], 0.f);
        float u2 = fmaxf((vv[t*4+2] - mean) * inv * g1v[t][2] + e1v[t][2], 0.f);
        float u3 = fmaxf((vv[t*4+3] - mean) * inv * g1v[t][3] + e1v[t][3], 0.f);
        int ch = (t * 2 + (g >> 1)) ^ (tokL & 3);
        uint2 wr; wr.x = pack2(u0, u1); wr.y = pack2(u2, u3);
        *(uint2*)&h_lds[tokL * 16 + ch * 4 + (g & 1) * 2] = wr;
      }
    }
  }

  // ================= P2: QKV projection (32 -> 96) =================
  {
    FragU wq[6], wql[6]; f32x4 bq[6];
#pragma unroll
    for (int ft = 0; ft < 6; ++ft) {
      wq[ft].q  = *(const uint4*)&ws[WS_WQH + (ft * 16 + li) * 16 + g * 4];
      wql[ft].q = *(const uint4*)&ws[WS_WQL + (ft * 16 + li) * 16 + g * 4];
#pragma unroll
      for (int r = 0; r < 4; ++r) bq[ft][r] = bqkv[ft * 16 + g * 4 + r];
    }
#pragma unroll
    for (int mt = 0; mt < 5; ++mt) {
      int tokL = rowW + mt * 16 + li;
      int ch = g ^ (tokL & 3);
      uint4 hv = *(const uint4*)&h_lds[tokL * 16 + ch * 4];
      FragU hb; hb.q = hv;
#pragma unroll
      for (int ft = 0; ft < 6; ++ft) {
        f32x4 acc = __builtin_amdgcn_mfma_f32_16x16x32_bf16(wq[ft].v,  hb.v, bq[ft], 0, 0, 0);
        acc       = __builtin_amdgcn_mfma_f32_16x16x32_bf16(wql[ft].v, hb.v, acc,    0, 0, 0);
        int chq = (ft * 2 + (g >> 1)) ^ (tokL & 3);
        uint2 wr; wr.x = pack2(acc[0], acc[1]); wr.y = pack2(acc[2], acc[3]);
        *(uint2*)&qkv_lds[tokL * 48 + chq * 4 + (g & 1) * 2] = wr;
      }
    }
  }

  // ================= attention: 2 lanes per (batch,head), d-split =================
  {
    int b_l = wv * 16 + (lane >> 2);
    int hh  = (lane >> 1) & 1;
    int cq  = hh * 2 + (lane & 1);      // q chunk (feats hh*16 + (lane&1)*8 .. +7)

    float q[5][8]; uint32_t kp[5][4], vp[5][4];
#pragma unroll
    for (int s = 0; s < 5; ++s) {
      int tok = b_l * 5 + s, key = tok & 3;
      uint4 qv = *(const uint4*)&qkv_lds[tok * 48 + (cq ^ key) * 4];
      up2(qv.x, q[s][0], q[s][1]); up2(qv.y, q[s][2], q[s][3]);
      up2(qv.z, q[s][4], q[s][5]); up2(qv.w, q[s][6], q[s][7]);
      uint4 kv = *(const uint4*)&qkv_lds[tok * 48 + ((4 + cq) ^ key) * 4];
      kp[s][0] = kv.x; kp[s][1] = kv.y; kp[s][2] = kv.z; kp[s][3] = kv.w;
      uint4 vv4 = *(const uint4*)&qkv_lds[tok * 48 + ((8 + cq) ^ key) * 4];
      vp[s][0] = vv4.x; vp[s][1] = vv4.y; vp[s][2] = vv4.z; vp[s][3] = vv4.w;
    }
    float sc[5][5];
#pragma unroll
    for (int s2 = 0; s2 < 5; ++s2) {
      float kr[8];
      up2(kp[s2][0], kr[0], kr[1]); up2(kp[s2][1], kr[2], kr[3]);
      up2(kp[s2][2], kr[4], kr[5]); up2(kp[s2][3], kr[6], kr[7]);
#pragma unroll
      for (int s1 = 0; s1 < 5; ++s1) {
        float p = 0.f;
#pragma unroll
        for (int j = 0; j < 8; ++j) p = fmaf(q[s1][j], kr[j], p);
        sc[s1][s2] = p;
      }
    }
#pragma unroll
    for (int s1 = 0; s1 < 5; ++s1)
#pragma unroll
      for (int s2 = 0; s2 < 5; ++s2) {
        float p = sc[s1][s2];
        p += __shfl_xor(p, 1);
        sc[s1][s2] = p * 0.25f;
      }
#pragma unroll
    for (int s1 = 0; s1 < 5; ++s1) {
      float m = fmaxf(fmaxf(fmaxf(sc[s1][0], sc[s1][1]), fmaxf(sc[s1][2], sc[s1][3])), sc[s1][4]);
      float ssum = 0.f;
#pragma unroll
      for (int s2 = 0; s2 < 5; ++s2) { float e = __expf(sc[s1][s2] - m); sc[s1][s2] = e; ssum += e; }
      float rs = 1.f / ssum;
#pragma unroll
      for (int s2 = 0; s2 < 5; ++s2) sc[s1][s2] *= rs;
    }
    float o[5][8];
#pragma unroll
    for (int s1 = 0; s1 < 5; ++s1)
#pragma unroll
      for (int j = 0; j < 8; ++j) o[s1][j] = 0.f;
#pragma unroll
    for (int s2 = 0; s2 < 5; ++s2) {
      float vr[8];
      up2(vp[s2][0], vr[0], vr[1]); up2(vp[s2][1], vr[2], vr[3]);
      up2(vp[s2][2], vr[4], vr[5]); up2(vp[s2][3], vr[6], vr[7]);
#pragma unroll
      for (int s1 = 0; s1 < 5; ++s1)
#pragma unroll
        for (int j = 0; j < 8; ++j) o[s1][j] = fmaf(sc[s1][s2], vr[j], o[s1][j]);
    }
#pragma unroll
    for (int s1 = 0; s1 < 5; ++s1) {
      int tok = b_l * 5 + s1;
      uint4 wr;
      wr.x = pack2(o[s1][0], o[s1][1]); wr.y = pack2(o[s1][2], o[s1][3]);
      wr.z = pack2(o[s1][4], o[s1][5]); wr.w = pack2(o[s1][6], o[s1][7]);
      *(uint4*)&qkv_lds[tok * 48 + (cq ^ (tok & 3)) * 4] = wr;
    }
  }

  // ================= P3: out_proj + residual + LN2 =================
  {
    FragU wof[2], wolf[2]; f32x4 binit[2]; float g2v[2][4], e2v[2][4];
#pragma unroll
    for (int t = 0; t < 2; ++t) {
      wof[t].q  = *(const uint4*)&ws[WS_WOH + (t * 16 + li) * 16 + g * 4];
      wolf[t].q = *(const uint4*)&ws[WS_WOL + (t * 16 + li) * 16 + g * 4];
#pragma unroll
      for (int r = 0; r < 4; ++r) {
        int n = t * 16 + g * 4 + r;
        binit[t][r] = bo[n]; g2v[t][r] = g2[n]; e2v[t][r] = be2[n];
      }
    }
#pragma unroll
    for (int mt = 0; mt < 5; ++mt) {
      int tokL = rowW + mt * 16 + li;
      int ch = g ^ (tokL & 3);
      uint4 ov = *(const uint4*)&qkv_lds[tokL * 48 + ch * 4];
      FragU ob; ob.q = ov;
      f32x4 a0 = __builtin_amdgcn_mfma_f32_16x16x32_bf16(wof[0].v,  ob.v, binit[0], 0, 0, 0);
      a0       = __builtin_amdgcn_mfma_f32_16x16x32_bf16(wolf[0].v, ob.v, a0,       0, 0, 0);
      f32x4 a1 = __builtin_amdgcn_mfma_f32_16x16x32_bf16(wof[1].v,  ob.v, binit[1], 0, 0, 0);
      a1       = __builtin_amdgcn_mfma_f32_16x16x32_bf16(wolf[1].v, ob.v, a1,       0, 0, 0);
      float vv[8];
#pragma unroll
      for (int t = 0; t < 2; ++t) {
        int chh = (t * 2 + (g >> 1)) ^ (tokL & 3);
        uint2 rh = *(const uint2*)&h_lds[tokL * 16 + chh * 4 + (g & 1) * 2];
        float r0, r1, r2, r3;
        up2(rh.x, r0, r1); up2(rh.y, r2, r3);
        if (t == 0) { vv[0] = a0[0] + r0; vv[1] = a0[1] + r1; vv[2] = a0[2] + r2; vv[3] = a0[3] + r3; }
        else        { vv[4] = a1[0] + r0; vv[5] = a1[1] + r1; vv[6] = a1[2] + r2; vv[7] = a1[3] + r3; }
      }
      float sm = 0.f, sq = 0.f;
#pragma unroll
      for (int i = 0; i < 8; ++i) { sm += vv[i]; sq = fmaf(vv[i], vv[i], sq); }
      sm += __shfl_xor(sm, 16); sm += __shfl_xor(sm, 32);
      sq += __shfl_xor(sq, 16); sq += __shfl_xor(sq, 32);
      float mean = sm * (1.f / 32.f);
      float inv  = rsqrtf(sq * (1.f / 32.f) - mean * mean + 1e-5f);
#pragma unroll
      for (int t = 0; t < 2; ++t) {
        float u0 = (vv[t*4+0] - mean) * inv * g2v[t][0] + e2v[t][0];
        float u1 = (vv[t*4+1] - mean) * inv * g2v[t][1] + e2v[t][1];
        float u2 = (vv[t*4+2] - mean) * inv * g2v[t][2] + e2v[t][2];
        float u3 = (vv[t*4+3] - mean) * inv * g2v[t][3] + e2v[t][3];
        int chh = (t * 2 + (g >> 1)) ^ (tokL & 3);
        uint2 wr; wr.x = pack2(u0, u1); wr.y = pack2(u2, u3);
        *(uint2*)&h_lds[tokL * 16 + chh * 4 + (g & 1) * 2] = wr;
      }
    }
  }

  // ================= P4: output_proj (160 -> 64) + LN3 =================
  {
    int batL = wv * 16 + li;
    f32x4 acc[4];
#pragma unroll
    for (int ot = 0; ot < 4; ++ot)
#pragma unroll
      for (int r = 0; r < 4; ++r) acc[ot][r] = b3[ot * 16 + g * 4 + r];
#pragma unroll
    for (int kt = 0; kt < 5; ++kt) {
      int tokL = batL * 5 + kt;
      int ch = g ^ (tokL & 3);
      uint4 hv = *(const uint4*)&h_lds[tokL * 16 + ch * 4];
      FragU hb; hb.q = hv;
#pragma unroll
      for (int ot = 0; ot < 4; ++ot) {
        FragU fh, fl;
        fh.q = *(const uint4*)&ws[WS_W3H + (ot * 16 + li) * 80 + kt * 16 + g * 4];
        fl.q = *(const uint4*)&ws[WS_W3L + (ot * 16 + li) * 80 + kt * 16 + g * 4];
        acc[ot] = __builtin_amdgcn_mfma_f32_16x16x32_bf16(fh.v, hb.v, acc[ot], 0, 0, 0);
        acc[ot] = __builtin_amdgcn_mfma_f32_16x16x32_bf16(fl.v, hb.v, acc[ot], 0, 0, 0);
      }
    }
    float vv[16], g3v[16], e3v[16];
#pragma unroll
    for (int ot = 0; ot < 4; ++ot)
#pragma unroll
      for (int r = 0; r < 4; ++r) {
        int n = ot * 16 + g * 4 + r;
        vv[ot*4+r] = acc[ot][r]; g3v[ot*4+r] = g3[n]; e3v[ot*4+r] = be3[n];
      }
    float sm = 0.f, sq = 0.f;
#pragma unroll
    for (int i = 0; i < 16; ++i) { sm += vv[i]; sq = fmaf(vv[i], vv[i], sq); }
    sm += __shfl_xor(sm, 16); sm += __shfl_xor(sm, 32);
    sq += __shfl_xor(sq, 16); sq += __shfl_xor(sq, 32);
    float mean = sm * (1.f / 64.f);
    float inv  = rsqrtf(sq * (1.f / 64.f) - mean * mean + 1e-5f);
    float* op = out + (size_t)(b0 + batL) * OUTD;
#pragma unroll
    for (int ot = 0; ot < 4; ++ot) {
      float4 st;
      st.x = (vv[ot*4+0] - mean) * inv * g3v[ot*4+0] + e3v[ot*4+0];
      st.y = (vv[ot*4+1] - mean) * inv * g3v[ot*4+1] + e3v[ot*4+1];
      st.z = (vv[ot*4+2] - mean) * inv * g3v[ot*4+2] + e3v[ot*4+2];
      st.w = (vv[ot*4+3] - mean) * inv * g3v[ot*4+3] + e3v[ot*4+3];
      *(float4*)&op[ot * 16 + g * 4] = st;
    }
  }
}

extern "C" void kernel_launch(void* const* d_in, const int* in_sizes, int n_in,
                              void* d_out, int out_size, void* d_ws, size_t ws_size,
                              hipStream_t stream) {
  const float* x    = (const float*)d_in[0];
  const float* W1   = (const float*)d_in[1];
  const float* b1   = (const float*)d_in[2];
  const float* g1   = (const float*)d_in[3];
  const float* be1  = (const float*)d_in[4];
  const float* Wqkv = (const float*)d_in[5];
  const float* bqkv = (const float*)d_in[6];
  const float* Wo   = (const float*)d_in[7];
  const float* bo   = (const float*)d_in[8];
  const float* g2   = (const float*)d_in[9];
  const float* be2  = (const float*)d_in[10];
  const float* W3   = (const float*)d_in[11];
  const float* b3   = (const float*)d_in[12];
  const float* g3   = (const float*)d_in[13];
  const float* be3  = (const float*)d_in[14];
  float* out = (float*)d_out;
  uint32_t* ws = (uint32_t*)d_ws;

  prep_weights<<<dim3((WS_TOTAL + 255) / 256), dim3(256), 0, stream>>>(W1, Wqkv, Wo, W3, ws);

  const int nbatch  = in_sizes[0] / SF;   // 262144
  const int nblocks = nbatch / TB;        // 8192

  fused_exec_encoder<<<dim3(nblocks), dim3(NTHR), 0, stream>>>(
      x, b1, g1, be1, bqkv, bo, g2, be2, b3, g3, be3, ws, out);
}

// Round 4
// 132.964 us; speedup vs baseline: 5.0908x; 1.0657x over previous
//
#include <hip/hip_runtime.h>
#include <hip/hip_bf16.h>
#include <stdint.h>

#define S    5
#define F    12
#define E    32
#define OUTD 64
#define SF   60
#define TB   32      // batches per block (16 per wave)
#define NTHR 128     // 2 waves, fully independent

// d_ws layout (u32 offsets)
#define WS_W1HI  0      // [32 rows][16 u32]  slots0-11=W1hi, rest 0
#define WS_W1LO  512    // [32][16]           slots0-11=W1lo, rest 0
#define WS_WQH   1024   // [96][16]
#define WS_WQL   2560   // [96][16]
#define WS_WOH   4096   // [32][16]
#define WS_WOL   4608   // [32][16]
#define WS_W3H   5120   // [64][80]
#define WS_W3L   10240  // [64][80]
#define WS_TOTAL 15360

typedef __attribute__((ext_vector_type(8))) short bf16x8;
typedef __attribute__((ext_vector_type(4))) float f32x4;

union FragU { bf16x8 v; uint32_t u[4]; uint4 q; };

// HW bf16 conversion (RNE) — compiler emits v_cvt_pk_bf16_f32
__device__ __forceinline__ uint32_t pack2(float lo, float hi) {
  __hip_bfloat16 a = __float2bfloat16(lo);
  __hip_bfloat16 b = __float2bfloat16(hi);
  uint16_t ua = __builtin_bit_cast(uint16_t, a);
  uint16_t ub = __builtin_bit_cast(uint16_t, b);
  return (uint32_t)ua | ((uint32_t)ub << 16);
}
__device__ __forceinline__ void up2(uint32_t w, float& lo, float& hi) {
  union { uint32_t u; float f; } a, b;
  a.u = w << 16; b.u = w & 0xffff0000u;
  lo = a.f; hi = b.f;
}
__device__ __forceinline__ uint16_t f2bf(float f) {   // prep only
  union { float f; uint32_t u; } c; c.f = f;
  uint32_t u = c.u + 0x7fffu + ((c.u >> 16) & 1u);
  return (uint16_t)(u >> 16);
}
__device__ __forceinline__ float bf2f(uint16_t h) {
  union { uint32_t u; float f; } c; c.u = ((uint32_t)h) << 16; return c.f;
}

// ---------------- prep: pack hi/lo bf16 weight planes into d_ws ----------------
__global__ void prep_weights(const float* __restrict__ W1, const float* __restrict__ Wqkv,
                             const float* __restrict__ Wo, const float* __restrict__ W3,
                             uint32_t* __restrict__ ws) {
  int i = blockIdx.x * blockDim.x + threadIdx.x;
  if (i >= WS_TOTAL) return;
  const float* W; int ldk, K, r, j; bool lo;
  if (i < 1024)      { W = W1;   ldk = 12;  K = 12;  int t = i;        lo = t >= 512;  t &= 511;  r = t >> 4; j = t & 15; }
  else if (i < 4096) { W = Wqkv; ldk = 32;  K = 32;  int t = i - 1024; lo = t >= 1536; t %= 1536; r = t >> 4; j = t & 15; }
  else if (i < 5120) { W = Wo;   ldk = 32;  K = 32;  int t = i - 4096; lo = t >= 512;  t &= 511;  r = t >> 4; j = t & 15; }
  else               { W = W3;   ldk = 160; K = 160; int t = i - 5120; lo = t >= 5120; t %= 5120; r = t / 80; j = t % 80; }
  float v2[2];
#pragma unroll
  for (int c = 0; c < 2; ++c) {
    int k = 2 * j + c;
    float w = 0.f;
    if (k < K) {
      w = W[r * ldk + k];
      if (lo) w = w - bf2f(f2bf(w));
    }
    v2[c] = w;
  }
  ws[i] = (uint32_t)f2bf(v2[0]) | (((uint32_t)f2bf(v2[1])) << 16);
}

__global__ __launch_bounds__(NTHR, 2) void fused_exec_encoder(
    const float* __restrict__ x,
    const float* __restrict__ b1,
    const float* __restrict__ g1,   const float* __restrict__ be1,
    const float* __restrict__ bqkv,
    const float* __restrict__ bo,
    const float* __restrict__ g2,   const float* __restrict__ be2,
    const float* __restrict__ b3,
    const float* __restrict__ g3,   const float* __restrict__ be3,
    const uint32_t* __restrict__ ws,
    float* __restrict__ out)
{
  // h:  [160 rows][16 u32]  (32 bf16/row, 4x16B chunks, chunk ^ (row&3) swizzle) = 10240 B
  // qkv:[160 rows][48 u32]  (96 bf16/row, 12x16B chunks, same swizzle)           = 30720 B
  __shared__ __align__(16) uint32_t h_lds[160 * 16];
  __shared__ __align__(16) uint32_t qkv_lds[160 * 48];

  const int tid  = threadIdx.x;
  const int lane = tid & 63;
  const int wv   = tid >> 6;          // wave id: owns batches [wv*16, wv*16+16)
  const int li   = lane & 15;         // token/col index within tile
  const int g    = lane >> 4;         // k-group / output-feature group
  const int rowW = wv * 80;           // wave's local token-row base
  const long long b0 = (long long)blockIdx.x * TB;

  // ================= P1: slot_encoder (Linear 12->32 + LN + ReLU) =================
  {
    FragU whi[2], wlo[2];
#pragma unroll
    for (int t = 0; t < 2; ++t) {
      whi[t].q = *(const uint4*)&ws[WS_W1HI + (t * 16 + li) * 16 + g * 4];
      wlo[t].q = *(const uint4*)&ws[WS_W1LO + (t * 16 + li) * 16 + g * 4];
    }
    f32x4 binit[2]; float g1v[2][4], e1v[2][4];
#pragma unroll
    for (int t = 0; t < 2; ++t)
#pragma unroll
      for (int r = 0; r < 4; ++r) {
        int n = t * 16 + g * 4 + r;
        binit[t][r] = b1[n]; g1v[t][r] = g1[n]; e1v[t][r] = be1[n];
      }

#pragma unroll
    for (int mt = 0; mt < 5; ++mt) {
      int tokL = rowW + mt * 16 + li;
      long long tokG = b0 * S + tokL;
      const float* xp = x + tokG * F;   // SF*4 = 240 = 5*48 -> token-contig
      FragU xb;
      xb.u[0] = xb.u[1] = xb.u[2] = xb.u[3] = 0u;
      if (g == 0) {
        float4 x0 = *(const float4*)(xp);
        float4 x1 = *(const float4*)(xp + 4);
        xb.u[0] = pack2(x0.x, x0.y); xb.u[1] = pack2(x0.z, x0.w);
        xb.u[2] = pack2(x1.x, x1.y); xb.u[3] = pack2(x1.z, x1.w);
      } else if (g == 1) {
        float4 x2 = *(const float4*)(xp + 8);
        xb.u[0] = pack2(x2.x, x2.y); xb.u[1] = pack2(x2.z, x2.w);
      }
      f32x4 a0 = __builtin_amdgcn_mfma_f32_16x16x32_bf16(whi[0].v, xb.v, binit[0], 0, 0, 0);
      a0       = __builtin_amdgcn_mfma_f32_16x16x32_bf16(wlo[0].v, xb.v, a0,       0, 0, 0);
      f32x4 a1 = __builtin_amdgcn_mfma_f32_16x16x32_bf16(whi[1].v, xb.v, binit[1], 0, 0, 0);
      a1       = __builtin_amdgcn_mfma_f32_16x16x32_bf16(wlo[1].v, xb.v, a1,       0, 0, 0);
      float vv[8];
#pragma unroll
      for (int r = 0; r < 4; ++r) { vv[r] = a0[r]; vv[4 + r] = a1[r]; }
      float sm = 0.f, sq = 0.f;
#pragma unroll
      for (int i = 0; i < 8; ++i) { sm += vv[i]; sq = fmaf(vv[i], vv[i], sq); }
      sm += __shfl_xor(sm, 16); sm += __shfl_xor(sm, 32);
      sq += __shfl_xor(sq, 16); sq += __shfl_xor(sq, 32);
      float mean = sm * (1.f / 32.f);
      float inv  = rsqrtf(sq * (1.f / 32.f) - mean * mean + 1e-5f);
#pragma unroll
      for (int t = 0; t < 2; ++t) {
        float u0 = fmaxf((vv[t*4+0] - mean) * inv * g1v[t][0] + e1v[t][0], 0.f);
        float u1 = fmaxf((vv[t*4+1] - mean) * inv * g1v[t][1] + e1v[t][1], 0.f);
        float u2 = fmaxf((vv[t*4+2] - mean) * inv * g1v[t][2] + e1v[t][2], 0.f);
        float u3 = fmaxf((vv[t*4+3] - mean) * inv * g1v[t][3] + e1v[t][3], 0.f);
        int ch = (t * 2 + (g >> 1)) ^ (tokL & 3);
        uint2 wr; wr.x = pack2(u0, u1); wr.y = pack2(u2, u3);
        *(uint2*)&h_lds[tokL * 16 + ch * 4 + (g & 1) * 2] = wr;
      }
    }
  }

  // ================= P2: QKV projection (32 -> 96) =================
  {
    FragU wq[6], wql[6]; f32x4 bq[6];
#pragma unroll
    for (int ft = 0; ft < 6; ++ft) {
      wq[ft].q  = *(const uint4*)&ws[WS_WQH + (ft * 16 + li) * 16 + g * 4];
      wql[ft].q = *(const uint4*)&ws[WS_WQL + (ft * 16 + li) * 16 + g * 4];
#pragma unroll
      for (int r = 0; r < 4; ++r) bq[ft][r] = bqkv[ft * 16 + g * 4 + r];
    }
#pragma unroll
    for (int mt = 0; mt < 5; ++mt) {
      int tokL = rowW + mt * 16 + li;
      int ch = g ^ (tokL & 3);
      uint4 hv = *(const uint4*)&h_lds[tokL * 16 + ch * 4];
      FragU hb; hb.q = hv;
#pragma unroll
      for (int ft = 0; ft < 6; ++ft) {
        f32x4 acc = __builtin_amdgcn_mfma_f32_16x16x32_bf16(wq[ft].v,  hb.v, bq[ft], 0, 0, 0);
        acc       = __builtin_amdgcn_mfma_f32_16x16x32_bf16(wql[ft].v, hb.v, acc,    0, 0, 0);
        int chq = (ft * 2 + (g >> 1)) ^ (tokL & 3);
        uint2 wr; wr.x = pack2(acc[0], acc[1]); wr.y = pack2(acc[2], acc[3]);
        *(uint2*)&qkv_lds[tokL * 48 + chq * 4 + (g & 1) * 2] = wr;
      }
    }
  }

  // ================= attention: 2 lanes per (batch,head), d-split =================
  {
    int b_l = wv * 16 + (lane >> 2);
    int hh  = (lane >> 1) & 1;
    int cq  = hh * 2 + (lane & 1);      // q chunk (feats hh*16 + (lane&1)*8 .. +7)

    float q[5][8]; uint32_t kp[5][4], vp[5][4];
#pragma unroll
    for (int s = 0; s < 5; ++s) {
      int tok = b_l * 5 + s, key = tok & 3;
      uint4 qv = *(const uint4*)&qkv_lds[tok * 48 + (cq ^ key) * 4];
      up2(qv.x, q[s][0], q[s][1]); up2(qv.y, q[s][2], q[s][3]);
      up2(qv.z, q[s][4], q[s][5]); up2(qv.w, q[s][6], q[s][7]);
      uint4 kv = *(const uint4*)&qkv_lds[tok * 48 + ((4 + cq) ^ key) * 4];
      kp[s][0] = kv.x; kp[s][1] = kv.y; kp[s][2] = kv.z; kp[s][3] = kv.w;
      uint4 vv4 = *(const uint4*)&qkv_lds[tok * 48 + ((8 + cq) ^ key) * 4];
      vp[s][0] = vv4.x; vp[s][1] = vv4.y; vp[s][2] = vv4.z; vp[s][3] = vv4.w;
    }
    float sc[5][5];
#pragma unroll
    for (int s2 = 0; s2 < 5; ++s2) {
      float kr[8];
      up2(kp[s2][0], kr[0], kr[1]); up2(kp[s2][1], kr[2], kr[3]);
      up2(kp[s2][2], kr[4], kr[5]); up2(kp[s2][3], kr[6], kr[7]);
#pragma unroll
      for (int s1 = 0; s1 < 5; ++s1) {
        float p = 0.f;
#pragma unroll
        for (int j = 0; j < 8; ++j) p = fmaf(q[s1][j], kr[j], p);
        sc[s1][s2] = p;
      }
    }
#pragma unroll
    for (int s1 = 0; s1 < 5; ++s1)
#pragma unroll
      for (int s2 = 0; s2 < 5; ++s2) {
        float p = sc[s1][s2];
        p += __shfl_xor(p, 1);
        sc[s1][s2] = p * 0.25f;
      }
#pragma unroll
    for (int s1 = 0; s1 < 5; ++s1) {
      float m = fmaxf(fmaxf(fmaxf(sc[s1][0], sc[s1][1]), fmaxf(sc[s1][2], sc[s1][3])), sc[s1][4]);
      float ssum = 0.f;
#pragma unroll
      for (int s2 = 0; s2 < 5; ++s2) { float e = __expf(sc[s1][s2] - m); sc[s1][s2] = e; ssum += e; }
      float rs = __builtin_amdgcn_rcpf(ssum);
#pragma unroll
      for (int s2 = 0; s2 < 5; ++s2) sc[s1][s2] *= rs;
    }
    float o[5][8];
#pragma unroll
    for (int s1 = 0; s1 < 5; ++s1)
#pragma unroll
      for (int j = 0; j < 8; ++j) o[s1][j] = 0.f;
#pragma unroll
    for (int s2 = 0; s2 < 5; ++s2) {
      float vr[8];
      up2(vp[s2][0], vr[0], vr[1]); up2(vp[s2][1], vr[2], vr[3]);
      up2(vp[s2][2], vr[4], vr[5]); up2(vp[s2][3], vr[6], vr[7]);
#pragma unroll
      for (int s1 = 0; s1 < 5; ++s1)
#pragma unroll
        for (int j = 0; j < 8; ++j) o[s1][j] = fmaf(sc[s1][s2], vr[j], o[s1][j]);
    }
#pragma unroll
    for (int s1 = 0; s1 < 5; ++s1) {
      int tok = b_l * 5 + s1;
      uint4 wr;
      wr.x = pack2(o[s1][0], o[s1][1]); wr.y = pack2(o[s1][2], o[s1][3]);
      wr.z = pack2(o[s1][4], o[s1][5]); wr.w = pack2(o[s1][6], o[s1][7]);
      *(uint4*)&qkv_lds[tok * 48 + (cq ^ (tok & 3)) * 4] = wr;
    }
  }

  // ================= P3: out_proj + residual + LN2 =================
  {
    FragU wof[2], wolf[2]; f32x4 binit[2]; float g2v[2][4], e2v[2][4];
#pragma unroll
    for (int t = 0; t < 2; ++t) {
      wof[t].q  = *(const uint4*)&ws[WS_WOH + (t * 16 + li) * 16 + g * 4];
      wolf[t].q = *(const uint4*)&ws[WS_WOL + (t * 16 + li) * 16 + g * 4];
#pragma unroll
      for (int r = 0; r < 4; ++r) {
        int n = t * 16 + g * 4 + r;
        binit[t][r] = bo[n]; g2v[t][r] = g2[n]; e2v[t][r] = be2[n];
      }
    }
#pragma unroll
    for (int mt = 0; mt < 5; ++mt) {
      int tokL = rowW + mt * 16 + li;
      int ch = g ^ (tokL & 3);
      uint4 ov = *(const uint4*)&qkv_lds[tokL * 48 + ch * 4];
      FragU ob; ob.q = ov;
      f32x4 a0 = __builtin_amdgcn_mfma_f32_16x16x32_bf16(wof[0].v,  ob.v, binit[0], 0, 0, 0);
      a0       = __builtin_amdgcn_mfma_f32_16x16x32_bf16(wolf[0].v, ob.v, a0,       0, 0, 0);
      f32x4 a1 = __builtin_amdgcn_mfma_f32_16x16x32_bf16(wof[1].v,  ob.v, binit[1], 0, 0, 0);
      a1       = __builtin_amdgcn_mfma_f32_16x16x32_bf16(wolf[1].v, ob.v, a1,       0, 0, 0);
      float vv[8];
#pragma unroll
      for (int t = 0; t < 2; ++t) {
        int chh = (t * 2 + (g >> 1)) ^ (tokL & 3);
        uint2 rh = *(const uint2*)&h_lds[tokL * 16 + chh * 4 + (g & 1) * 2];
        float r0, r1, r2, r3;
        up2(rh.x, r0, r1); up2(rh.y, r2, r3);
        if (t == 0) { vv[0] = a0[0] + r0; vv[1] = a0[1] + r1; vv[2] = a0[2] + r2; vv[3] = a0[3] + r3; }
        else        { vv[4] = a1[0] + r0; vv[5] = a1[1] + r1; vv[6] = a1[2] + r2; vv[7] = a1[3] + r3; }
      }
      float sm = 0.f, sq = 0.f;
#pragma unroll
      for (int i = 0; i < 8; ++i) { sm += vv[i]; sq = fmaf(vv[i], vv[i], sq); }
      sm += __shfl_xor(sm, 16); sm += __shfl_xor(sm, 32);
      sq += __shfl_xor(sq, 16); sq += __shfl_xor(sq, 32);
      float mean = sm * (1.f / 32.f);
      float inv  = rsqrtf(sq * (1.f / 32.f) - mean * mean + 1e-5f);
#pragma unroll
      for (int t = 0; t < 2; ++t) {
        float u0 = (vv[t*4+0] - mean) * inv * g2v[t][0] + e2v[t][0];
        float u1 = (vv[t*4+1] - mean) * inv * g2v[t][1] + e2v[t][1];
        float u2 = (vv[t*4+2] - mean) * inv * g2v[t][2] + e2v[t][2];
        float u3 = (vv[t*4+3] - mean) * inv * g2v[t][3] + e2v[t][3];
        int chh = (t * 2 + (g >> 1)) ^ (tokL & 3);
        uint2 wr; wr.x = pack2(u0, u1); wr.y = pack2(u2, u3);
        *(uint2*)&h_lds[tokL * 16 + chh * 4 + (g & 1) * 2] = wr;
      }
    }
  }

  // ================= P4: output_proj (160 -> 64) + LN3 =================
  {
    int batL = wv * 16 + li;
    f32x4 acc[4];
#pragma unroll
    for (int ot = 0; ot < 4; ++ot)
#pragma unroll
      for (int r = 0; r < 4; ++r) acc[ot][r] = b3[ot * 16 + g * 4 + r];
#pragma unroll
    for (int kt = 0; kt < 5; ++kt) {
      int tokL = batL * 5 + kt;
      int ch = g ^ (tokL & 3);
      uint4 hv = *(const uint4*)&h_lds[tokL * 16 + ch * 4];
      FragU hb; hb.q = hv;
#pragma unroll
      for (int ot = 0; ot < 4; ++ot) {
        FragU fh, fl;
        fh.q = *(const uint4*)&ws[WS_W3H + (ot * 16 + li) * 80 + kt * 16 + g * 4];
        fl.q = *(const uint4*)&ws[WS_W3L + (ot * 16 + li) * 80 + kt * 16 + g * 4];
        acc[ot] = __builtin_amdgcn_mfma_f32_16x16x32_bf16(fh.v, hb.v, acc[ot], 0, 0, 0);
        acc[ot] = __builtin_amdgcn_mfma_f32_16x16x32_bf16(fl.v, hb.v, acc[ot], 0, 0, 0);
      }
    }
    float vv[16], g3v[16], e3v[16];
#pragma unroll
    for (int ot = 0; ot < 4; ++ot)
#pragma unroll
      for (int r = 0; r < 4; ++r) {
        int n = ot * 16 + g * 4 + r;
        vv[ot*4+r] = acc[ot][r]; g3v[ot*4+r] = g3[n]; e3v[ot*4+r] = be3[n];
      }
    float sm = 0.f, sq = 0.f;
#pragma unroll
    for (int i = 0; i < 16; ++i) { sm += vv[i]; sq = fmaf(vv[i], vv[i], sq); }
    sm += __shfl_xor(sm, 16); sm += __shfl_xor(sm, 32);
    sq += __shfl_xor(sq, 16); sq += __shfl_xor(sq, 32);
    float mean = sm * (1.f / 64.f);
    float inv  = rsqrtf(sq * (1.f / 64.f) - mean * mean + 1e-5f);
    float* op = out + (size_t)(b0 + batL) * OUTD;
#pragma unroll
    for (int ot = 0; ot < 4; ++ot) {
      float4 st;
      st.x = (vv[ot*4+0] - mean) * inv * g3v[ot*4+0] + e3v[ot*4+0];
      st.y = (vv[ot*4+1] - mean) * inv * g3v[ot*4+1] + e3v[ot*4+1];
      st.z = (vv[ot*4+2] - mean) * inv * g3v[ot*4+2] + e3v[ot*4+2];
      st.w = (vv[ot*4+3] - mean) * inv * g3v[ot*4+3] + e3v[ot*4+3];
      *(float4*)&op[ot * 16 + g * 4] = st;
    }
  }
}

extern "C" void kernel_launch(void* const* d_in, const int* in_sizes, int n_in,
                              void* d_out, int out_size, void* d_ws, size_t ws_size,
                              hipStream_t stream) {
  const float* x    = (const float*)d_in[0];
  const float* W1   = (const float*)d_in[1];
  const float* b1   = (const float*)d_in[2];
  const float* g1   = (const float*)d_in[3];
  const float* be1  = (const float*)d_in[4];
  const float* Wqkv = (const float*)d_in[5];
  const float* bqkv = (const float*)d_in[6];
  const float* Wo   = (const float*)d_in[7];
  const float* bo   = (const float*)d_in[8];
  const float* g2   = (const float*)d_in[9];
  const float* be2  = (const float*)d_in[10];
  const float* W3   = (const float*)d_in[11];
  const float* b3   = (const float*)d_in[12];
  const float* g3   = (const float*)d_in[13];
  const float* be3  = (const float*)d_in[14];
  float* out = (float*)d_out;
  uint32_t* ws = (uint32_t*)d_ws;

  prep_weights<<<dim3((WS_TOTAL + 255) / 256), dim3(256), 0, stream>>>(W1, Wqkv, Wo, W3, ws);

  const int nbatch  = in_sizes[0] / SF;   // 262144
  const int nblocks = nbatch / TB;        // 8192

  fused_exec_encoder<<<dim3(nblocks), dim3(NTHR), 0, stream>>>(
      x, b1, g1, be1, bqkv, bo, g2, be2, b3, g3, be3, ws, out);
}